// Round 9
// baseline (1096.183 us; speedup 1.0000x reference)
//
#include <hip/hip_runtime.h>

#define D    128
#define OD   384   // 3*D output row stride
#define NK   25    // KS^2 kernels
#define KC   5     // k per chunk = one i1-row
#define AST  132   // accum row stride in f32 (128 + 4 pad)

typedef __attribute__((ext_vector_type(8))) short bf16x8;
typedef __attribute__((ext_vector_type(4))) float f32x4;
typedef __attribute__((ext_vector_type(4))) unsigned int u32x4;

struct __align__(16) Rec {
  int src;           // source node
  int i0;            // 0..3
  unsigned int b01;  // f16 pair: (1-f0)(1-f1) | f0(1-f1)  -> lower i1-row corners
  unsigned int b23;  // f16 pair: (1-f0)f1 | f0*f1         -> upper i1-row corners
};

__device__ inline unsigned short f2bf(float f) {
  unsigned int u = __float_as_uint(f);
  u += 0x7fffu + ((u >> 16) & 1u);
  return (unsigned short)(u >> 16);
}
__device__ inline unsigned short f2h(float f) {
  return __builtin_bit_cast(unsigned short, (_Float16)f);
}
__device__ inline float h2f(unsigned int bits16) {
  return (float)__builtin_bit_cast(_Float16, (unsigned short)(bits16 & 0xffffu));
}

// ---------------- preprocessing: sort edges by (dst, i1-class) ---------------

__global__ __launch_bounds__(256) void count4_kernel(const int* __restrict__ dstA,
    const float* __restrict__ attr, int E, int* __restrict__ deg,
    int* __restrict__ cnt4) {
  int e = blockIdx.x * 256 + threadIdx.x;
  if (e >= E) return;
  int d = dstA[e];
  atomicAdd(&deg[d], 1);
  float v1 = attr[2 * e + 1] * 4.0f;
  int i1 = min(3, max(0, (int)v1));
  atomicAdd(&cnt4[d * 4 + i1], 1);
}

// parallel exclusive scan over cnt[M] -> base[M+1], cursor[M]
__global__ __launch_bounds__(1024) void scan_a_kernel(const int* __restrict__ cnt, int M,
    int* __restrict__ base, int* __restrict__ bsum) {
  __shared__ int tmp[1024];
  int tid = threadIdx.x;
  int e = blockIdx.x * 1024 + tid;
  int v = (e < M) ? cnt[e] : 0;
  tmp[tid] = v;
  __syncthreads();
#pragma unroll
  for (int off = 1; off < 1024; off <<= 1) {
    int t = (tid >= off) ? tmp[tid - off] : 0;
    __syncthreads();
    tmp[tid] += t;
    __syncthreads();
  }
  if (e <= M) base[e] = tmp[tid] - v;  // exclusive
  if (tid == 1023) bsum[blockIdx.x] = tmp[1023];
}

__global__ __launch_bounds__(256) void scan_b_kernel(int* __restrict__ bsum, int nblk) {
  __shared__ int tmp[256];
  __shared__ int carry;
  int tid = threadIdx.x;
  if (tid == 0) carry = 0;
  __syncthreads();
  for (int s = 0; s < nblk; s += 256) {
    int i = s + tid;
    int v = (i < nblk) ? bsum[i] : 0;
    tmp[tid] = v;
    __syncthreads();
#pragma unroll
    for (int off = 1; off < 256; off <<= 1) {
      int t = (tid >= off) ? tmp[tid - off] : 0;
      __syncthreads();
      tmp[tid] += t;
      __syncthreads();
    }
    if (i < nblk) bsum[i] = carry + tmp[tid] - v;
    __syncthreads();
    if (tid == 255) carry += tmp[255];
    __syncthreads();
  }
}

__global__ __launch_bounds__(256) void scan_c_kernel(int* __restrict__ base,
    int* __restrict__ cursor, const int* __restrict__ bsum, int M) {
  int e = blockIdx.x * 256 + threadIdx.x;
  if (e > M) return;
  int v = base[e] + bsum[e >> 10];
  base[e] = v;
  if (e < M) cursor[e] = v;
}

__global__ __launch_bounds__(256) void fill_kernel(const int* __restrict__ srcA,
    const int* __restrict__ dstA, const float* __restrict__ attr, int E,
    int* __restrict__ cursor, Rec* __restrict__ recs) {
  int e = blockIdx.x * 256 + threadIdx.x;
  if (e >= E) return;
  int d = dstA[e];
  float v0 = attr[2 * e] * 4.0f;
  float v1 = attr[2 * e + 1] * 4.0f;
  int i0 = min(3, max(0, (int)v0));
  int i1 = min(3, max(0, (int)v1));
  float f0 = v0 - (float)i0;
  float f1 = v1 - (float)i1;
  int pos = atomicAdd(&cursor[d * 4 + i1], 1);
  Rec r;
  r.src = srcA[e];
  r.i0 = i0;
  r.b01 = (unsigned int)f2h((1.f - f0) * (1.f - f1)) |
          ((unsigned int)f2h(f0 * (1.f - f1)) << 16);
  r.b23 = (unsigned int)f2h((1.f - f0) * f1) | ((unsigned int)f2h(f0 * f1) << 16);
  recs[pos] = r;
}

// WT[n][kk] = bf16(W[kk/128][kk%128][n]), kk = k*128+i flattened, per layer
__global__ __launch_bounds__(256) void wt_kernel(const float* __restrict__ W,
                                                 unsigned short* __restrict__ WT) {
  int idx = blockIdx.x * 256 + threadIdx.x;  // over 128*3200
  if (idx >= 128 * NK * D) return;
  int n = idx / (NK * D);
  int kk = idx - n * (NK * D);
  WT[idx] = f2bf(W[(size_t)kk * D + n]);
}

// ---------------- fused gather+MFMA per k-chunk (i1-row) ---------------------
// 1024 thr = 16 waves; wave w owns dst blk*16+w with PRIVATE LDS accum [5][132]
// f32. One barrier, then MFMA: wave (nb,kh) -> 16x16 y-tile over its K-half.
// G never touches global memory.

__global__ __launch_bounds__(1024, 8) void fused_kernel(
    const int* __restrict__ base4, const Rec* __restrict__ recs,
    const unsigned short* __restrict__ Xb, const unsigned short* __restrict__ WT,
    float* __restrict__ Y, int N, int chunk) {
  __shared__ float lacc[16 * KC * AST];  // 42.2 KB
  __shared__ float red[8][256];          // 8 KB: kh=1 partials
  const int tid = threadIdx.x;
  const int w = tid >> 6, l = tid & 63;
  const int blk = blockIdx.x;
  const int dst = blk * 16 + w;
  float* A = lacc + w * (KC * AST);
  for (int t = l; t < KC * AST; t += 64) A[t] = 0.f;

  if (dst < N) {
    const int l2 = l * 2;
    auto ACC2 = [&](const Rec& r, unsigned int xp, bool upper) {
      unsigned int pair = upper ? r.b23 : r.b01;
      float w0 = h2f(pair), w1 = h2f(pair >> 16);
      float x0 = __uint_as_float(xp << 16);
      float x1 = __uint_as_float(xp & 0xffff0000u);
      float* p = A + r.i0 * AST + l2;
      float2 a0 = *(float2*)p;
      float2 a1 = *(float2*)(p + AST);
      a0.x = fmaf(w0, x0, a0.x); a0.y = fmaf(w0, x1, a0.y);
      a1.x = fmaf(w1, x0, a1.x); a1.y = fmaf(w1, x1, a1.y);
      *(float2*)p = a0;
      *(float2*)(p + AST) = a1;
    };
    auto WALK = [&](int j0, int j1, bool upper) {
      int j = j0;
      for (; j + 3 < j1; j += 4) {
        Rec r0 = recs[j], r1 = recs[j + 1], r2 = recs[j + 2], r3 = recs[j + 3];
        unsigned int xp0 = *(const unsigned int*)(Xb + (size_t)r0.src * D + l2);
        unsigned int xp1 = *(const unsigned int*)(Xb + (size_t)r1.src * D + l2);
        unsigned int xp2 = *(const unsigned int*)(Xb + (size_t)r2.src * D + l2);
        unsigned int xp3 = *(const unsigned int*)(Xb + (size_t)r3.src * D + l2);
        ACC2(r0, xp0, upper); ACC2(r1, xp1, upper);
        ACC2(r2, xp2, upper); ACC2(r3, xp3, upper);
      }
      for (; j < j1; ++j) {
        Rec r = recs[j];
        unsigned int xp = *(const unsigned int*)(Xb + (size_t)r.src * D + l2);
        ACC2(r, xp, upper);
      }
    };
    const int* b4 = base4 + dst * 4;
    if (chunk >= 1) {  // upper corners from class chunk-1
      int a0 = __builtin_amdgcn_readfirstlane(b4[chunk - 1]);
      int a1 = __builtin_amdgcn_readfirstlane(b4[chunk]);
      WALK(a0, a1, true);
    }
    if (chunk <= 3) {  // lower corners from class chunk
      int a0 = __builtin_amdgcn_readfirstlane(b4[chunk]);
      int a1 = __builtin_amdgcn_readfirstlane(b4[chunk + 1]);
      WALK(a0, a1, false);
    }
  }
  __syncthreads();

  // MFMA: A = lacc rows 0..15 (dsts), K = KC*128; wave (nb,kh) does 16 cols,
  // K-half; 10 k-steps of 32.
  const int nb = w & 7, kh = w >> 3;
  const int arow = l & 15, aoff = (l >> 4) * 8;
  const unsigned short* wb =
      WT + (size_t)(nb * 16 + arow) * (NK * D) + chunk * (KC * D);
  f32x4 acc = (f32x4){0.f, 0.f, 0.f, 0.f};
  for (int s = kh * (KC * 2); s < (kh + 1) * (KC * 2); ++s) {
    const float* ap =
        lacc + (size_t)arow * (KC * AST) + (s >> 2) * AST + (s & 3) * 32 + aoff;
    float4 fa = *(const float4*)ap;
    float4 fb = *(const float4*)(ap + 4);
    u32x4 pk;
    asm("v_cvt_pk_bf16_f32 %0, %1, %2" : "=v"(pk[0]) : "v"(fa.x), "v"(fa.y));
    asm("v_cvt_pk_bf16_f32 %0, %1, %2" : "=v"(pk[1]) : "v"(fa.z), "v"(fa.w));
    asm("v_cvt_pk_bf16_f32 %0, %1, %2" : "=v"(pk[2]) : "v"(fb.x), "v"(fb.y));
    asm("v_cvt_pk_bf16_f32 %0, %1, %2" : "=v"(pk[3]) : "v"(fb.z), "v"(fb.w));
    bf16x8 av = __builtin_bit_cast(bf16x8, pk);
    bf16x8 bv = *(const bf16x8*)(wb + s * 32 + aoff);
    acc = __builtin_amdgcn_mfma_f32_16x16x32_bf16(av, bv, acc, 0, 0, 0);
  }
  if (kh == 1) *(f32x4*)&red[nb][l * 4] = acc;
  __syncthreads();
  if (kh == 0) {
    f32x4 o = *(const f32x4*)&red[nb][l * 4];
    int col = nb * 16 + arow;
#pragma unroll
    for (int j = 0; j < 4; ++j) {
      int row = blk * 16 + (l >> 4) * 4 + j;
      if (row < N) {
        float v = acc[j] + o[j];
        float* yp = Y + (size_t)row * D + col;
        *yp = (chunk == 0) ? v : (*yp + v);
      }
    }
  }
}

// ---------------- per-row l2norm / finalize ----------------------------------

__global__ __launch_bounds__(256) void l2norm_x_kernel(const float* __restrict__ x,
    float* __restrict__ out, unsigned short* __restrict__ xbf, int N) {
  int g = blockIdx.x * 256 + threadIdx.x;
  int n = g >> 6, lane = g & 63;
  if (n >= N) return;
  float2 v = *(const float2*)(x + (size_t)n * D + lane * 2);
  float ss = v.x * v.x + v.y * v.y;
#pragma unroll
  for (int m = 1; m < 64; m <<= 1) ss += __shfl_xor(ss, m, 64);
  float r = 1.0f / fmaxf(sqrtf(ss), 1e-12f);
  *(float2*)(out + (size_t)n * OD + lane * 2) = make_float2(v.x * r, v.y * r);
  unsigned int pk = (unsigned int)f2bf(v.x) | ((unsigned int)f2bf(v.y) << 16);
  *(unsigned int*)(xbf + (size_t)n * D + lane * 2) = pk;
}

__global__ __launch_bounds__(256) void finalize_kernel(const float* __restrict__ y,
    const int* __restrict__ deg, const float* __restrict__ bias, float* __restrict__ out,
    unsigned short* __restrict__ xnext, int N) {
  int g = blockIdx.x * 256 + threadIdx.x;
  int n = g >> 6, lane = g & 63;
  if (n >= N) return;
  float inv = 1.0f / (float)max(deg[n], 1);
  float2 a = *(const float2*)(y + (size_t)n * D + lane * 2);
  float2 b = *(const float2*)(bias + lane * 2);
  float h0 = a.x * inv + b.x;
  float h1 = a.y * inv + b.y;
  float ss = h0 * h0 + h1 * h1;
#pragma unroll
  for (int m = 1; m < 64; m <<= 1) ss += __shfl_xor(ss, m, 64);
  float r = 1.0f / fmaxf(sqrtf(ss), 1e-12f);
  *(float2*)(out + (size_t)n * OD + lane * 2) = make_float2(h0 * r, h1 * r);
  if (xnext) {
    unsigned int pk = (unsigned int)f2bf(fmaxf(h0, 0.f)) |
                      ((unsigned int)f2bf(fmaxf(h1, 0.f)) << 16);
    *(unsigned int*)(xnext + (size_t)n * D + lane * 2) = pk;
  }
}

// ---------------- launch -----------------------------------------------------

extern "C" void kernel_launch(void* const* d_in, const int* in_sizes, int n_in,
                              void* d_out, int out_size, void* d_ws, size_t ws_size,
                              hipStream_t stream) {
  const float* x    = (const float*)d_in[0];
  const int*   ei   = (const int*)d_in[1];
  const float* attr = (const float*)d_in[2];
  const float* w0   = (const float*)d_in[3];
  const float* b0   = (const float*)d_in[4];
  const float* w1   = (const float*)d_in[5];
  const float* b1   = (const float*)d_in[6];
  float* out = (float*)d_out;

  const int N = in_sizes[0] / D;
  const int E = in_sizes[1] / 2;
  const int* srcA = ei;
  const int* dstA = ei + E;
  const int M4 = N * 4;

  char* p = (char*)d_ws;
  auto carve = [&](size_t bytes) -> char* {
    char* r = p;
    p += (bytes + 255) & ~(size_t)255;
    return r;
  };
  unsigned short* xbf    = (unsigned short*)carve((size_t)N * D * 2);
  unsigned short* xtmp   = (unsigned short*)carve((size_t)N * D * 2);
  float*          ygemm  = (float*)carve((size_t)N * D * 4);
  int*            deg    = (int*)carve((size_t)N * 4);
  int*            cnt4   = (int*)carve((size_t)M4 * 4);
  int*            base4  = (int*)carve(((size_t)M4 + 1) * 4);
  int*            cursor = (int*)carve((size_t)M4 * 4);
  int*            bsum   = (int*)carve(4096);
  Rec*            recs   = (Rec*)carve((size_t)E * sizeof(Rec));
  unsigned short* WT0    = (unsigned short*)carve((size_t)128 * NK * D * 2);
  unsigned short* WT1    = (unsigned short*)carve((size_t)128 * NK * D * 2);
  (void)n_in; (void)out_size; (void)ws_size;

  hipMemsetAsync(deg, 0, (size_t)N * 4, stream);
  hipMemsetAsync(cnt4, 0, (size_t)M4 * 4, stream);

  int eb = (E + 255) / 256;
  count4_kernel<<<eb, 256, 0, stream>>>(dstA, attr, E, deg, cnt4);
  int nblk_a = (M4 + 1 + 1023) / 1024;
  scan_a_kernel<<<nblk_a, 1024, 0, stream>>>(cnt4, M4, base4, bsum);
  scan_b_kernel<<<1, 256, 0, stream>>>(bsum, nblk_a);
  scan_c_kernel<<<(M4 + 1 + 255) / 256, 256, 0, stream>>>(base4, cursor, bsum, M4);
  fill_kernel<<<eb, 256, 0, stream>>>(srcA, dstA, attr, E, cursor, recs);
  int wtb = (128 * NK * D + 255) / 256;
  wt_kernel<<<wtb, 256, 0, stream>>>(w0, WT0);
  wt_kernel<<<wtb, 256, 0, stream>>>(w1, WT1);

  int nb = (N * 64 + 255) / 256;
  l2norm_x_kernel<<<nb, 256, 0, stream>>>(x, out, xbf, N);

  int fblk = (N + 15) / 16;  // fused: 16 dsts per 1024-thr block
  const unsigned short* xin = xbf;
  const float* Bv[2] = {b0, b1};
  const unsigned short* WTl[2] = {WT0, WT1};
  for (int layer = 0; layer < 2; ++layer) {
    for (int c = 0; c < 5; ++c)
      fused_kernel<<<fblk, 1024, 0, stream>>>(base4, recs, xin, WTl[layer], ygemm, N, c);
    finalize_kernel<<<nb, 256, 0, stream>>>(ygemm, deg, Bv[layer], out + D * (layer + 1),
                                            layer == 0 ? xtmp : nullptr, N);
    xin = xtmp;
  }
}

// Round 10
// 627.604 us; speedup vs baseline: 1.7466x; 1.7466x over previous
//
#include <hip/hip_runtime.h>

#define D     128
#define OD    384   // 3*D output row stride
#define NK    25    // KS^2 kernels
#define KCMAX 13    // k-chunk: G chunk 166MB bf16 stays L3-resident
#define KB0   13    // chunk boundary: pass0 = k in [0,13), pass1 = [13,25)

typedef __attribute__((ext_vector_type(8))) short bf16x8;
typedef __attribute__((ext_vector_type(4))) float f32x4;
typedef __attribute__((ext_vector_type(4))) unsigned int u32x4;
typedef const __attribute__((address_space(1))) void gv_t;
typedef __attribute__((address_space(3))) void lv_t;

struct __align__(16) Rec {
  int src;
  unsigned int wi;   // 4 x 5-bit corner kernel indices
  unsigned int b01;  // f16 weights q0|q1
  unsigned int b23;  // f16 weights q2|q3
};

__device__ inline unsigned short f2bf(float f) {
  unsigned int u = __float_as_uint(f);
  u += 0x7fffu + ((u >> 16) & 1u);
  return (unsigned short)(u >> 16);
}
__device__ inline unsigned short f2h(float f) {
  return __builtin_bit_cast(unsigned short, (_Float16)f);
}
__device__ inline float h2f(unsigned int bits16) {
  return (float)__builtin_bit_cast(_Float16, (unsigned short)(bits16 & 0xffffu));
}

// ---------------- preprocessing: sort edges by (dst, chunk-class) -----------
// class 0: all corners < KB0; class 2: all corners >= KB0; class 1: straddle.

__device__ inline int edge_cls(int w00) {
  return (w00 + 6 < KB0) ? 0 : ((w00 >= KB0) ? 2 : 1);
}

__global__ __launch_bounds__(256) void count3_kernel(const int* __restrict__ dstA,
    const float* __restrict__ attr, int E, int* __restrict__ deg,
    int* __restrict__ cnt3) {
  int e = blockIdx.x * 256 + threadIdx.x;
  if (e >= E) return;
  int d = dstA[e];
  atomicAdd(&deg[d], 1);
  float v0 = attr[2 * e] * 4.0f;
  float v1 = attr[2 * e + 1] * 4.0f;
  int i0 = min(3, max(0, (int)v0));
  int i1 = min(3, max(0, (int)v1));
  int w00 = i0 + 5 * i1;
  atomicAdd(&cnt3[d * 3 + edge_cls(w00)], 1);
}

// ---------------- parallel exclusive scan over cnt[M] -> base3[M+1] ----------

__global__ __launch_bounds__(1024) void scan_a_kernel(const int* __restrict__ cnt, int M,
    int* __restrict__ base3, int* __restrict__ bsum) {
  __shared__ int tmp[1024];
  int tid = threadIdx.x;
  int e = blockIdx.x * 1024 + tid;
  int v = (e < M) ? cnt[e] : 0;
  tmp[tid] = v;
  __syncthreads();
#pragma unroll
  for (int off = 1; off < 1024; off <<= 1) {
    int t = (tid >= off) ? tmp[tid - off] : 0;
    __syncthreads();
    tmp[tid] += t;
    __syncthreads();
  }
  if (e <= M) base3[e] = tmp[tid] - v;  // exclusive
  if (tid == 1023) bsum[blockIdx.x] = tmp[1023];
}

__global__ __launch_bounds__(256) void scan_b_kernel(int* __restrict__ bsum, int nblk) {
  __shared__ int tmp[256];
  __shared__ int carry;
  int tid = threadIdx.x;
  if (tid == 0) carry = 0;
  __syncthreads();
  for (int s = 0; s < nblk; s += 256) {
    int i = s + tid;
    int v = (i < nblk) ? bsum[i] : 0;
    tmp[tid] = v;
    __syncthreads();
#pragma unroll
    for (int off = 1; off < 256; off <<= 1) {
      int t = (tid >= off) ? tmp[tid - off] : 0;
      __syncthreads();
      tmp[tid] += t;
      __syncthreads();
    }
    if (i < nblk) bsum[i] = carry + tmp[tid] - v;
    __syncthreads();
    if (tid == 255) carry += tmp[255];
    __syncthreads();
  }
}

__global__ __launch_bounds__(256) void scan_c_kernel(int* __restrict__ base3,
    int* __restrict__ cursor, const int* __restrict__ bsum, int M) {
  int e = blockIdx.x * 256 + threadIdx.x;
  if (e > M) return;
  int v = base3[e] + bsum[e >> 10];
  base3[e] = v;
  if (e < M) cursor[e] = v;
}

__global__ __launch_bounds__(256) void fill_kernel(const int* __restrict__ srcA,
    const int* __restrict__ dstA, const float* __restrict__ attr, int E,
    int* __restrict__ cursor, Rec* __restrict__ recs) {
  int e = blockIdx.x * 256 + threadIdx.x;
  if (e >= E) return;
  int d = dstA[e];
  float v0 = attr[2 * e] * 4.0f;
  float v1 = attr[2 * e + 1] * 4.0f;
  int i0 = min(3, max(0, (int)v0));
  int i1 = min(3, max(0, (int)v1));
  float f0 = v0 - (float)i0;
  float f1 = v1 - (float)i1;
  int w00 = i0 + 5 * i1;
  int pos = atomicAdd(&cursor[d * 3 + edge_cls(w00)], 1);
  Rec r;
  r.src = srcA[e];
  unsigned int w = (unsigned int)w00;
  r.wi = w | ((w + 1) << 5) | ((w + 5) << 10) | ((w + 6) << 15);
  r.b01 = (unsigned int)f2h((1.f - f0) * (1.f - f1)) | ((unsigned int)f2h(f0 * (1.f - f1)) << 16);
  r.b23 = (unsigned int)f2h((1.f - f0) * f1) | ((unsigned int)f2h(f0 * f1) << 16);
  recs[pos] = r;
}

// WT[n][kk] = bf16(W[kk/128][kk%128][n]); gridDim.y selects layer
__global__ __launch_bounds__(256) void wt_kernel(const float* __restrict__ W0,
    const float* __restrict__ W1, unsigned short* __restrict__ WT0,
    unsigned short* __restrict__ WT1) {
  int idx = blockIdx.x * 256 + threadIdx.x;  // over 128*3200
  if (idx >= 128 * NK * D) return;
  const float* W = blockIdx.y ? W1 : W0;
  unsigned short* WT = blockIdx.y ? WT1 : WT0;
  int n = idx / (NK * D);
  int kk = idx - n * (NK * D);
  WT[idx] = f2bf(W[(size_t)kk * D + n]);
}

// ---------------- gather: G[dst, k-chunk, :] = sum b * x[src] (bf16 in/out) --
// wave per dst, per-wave LDS f32 accumulator; predicated 4-deep batches with
// software-pipelined record prefetch (no scalar tail).

__global__ __launch_bounds__(256) void gather_kernel(const int* __restrict__ base3,
    const Rec* __restrict__ recs, const unsigned short* __restrict__ Xb,
    unsigned short* __restrict__ Gc, int N, int KCc, int kc0, int c_lo, int c_hi) {
  __shared__ float lacc[4][KCMAX * D];
  int w = threadIdx.x >> 6, l = threadIdx.x & 63;
  int dst = blockIdx.x * 4 + w;
  if (dst >= N) return;
  float* A = lacc[w];
  for (int k = 0; k < KCc; ++k)
    *(float2*)(A + k * D + l * 2) = make_float2(0.f, 0.f);

  const int l2 = l * 2;
  auto ACC = [&](const Rec& r, unsigned int xp) {
    float x0 = __uint_as_float(xp << 16);
    float x1 = __uint_as_float(xp & 0xffff0000u);
    float bq[4] = {h2f(r.b01), h2f(r.b01 >> 16), h2f(r.b23), h2f(r.b23 >> 16)};
#pragma unroll
    for (int q = 0; q < 4; ++q) {
      int k = (int)((r.wi >> (5 * q)) & 31u) - kc0;
      if ((unsigned)k < (unsigned)KCc) {
        float2 p = *(const float2*)(A + k * D + l2);
        p.x = fmaf(bq[q], x0, p.x);
        p.y = fmaf(bq[q], x1, p.y);
        *(float2*)(A + k * D + l2) = p;
      }
    }
  };

  int s = __builtin_amdgcn_readfirstlane(base3[dst * 3 + c_lo]);
  int e = __builtin_amdgcn_readfirstlane(base3[dst * 3 + c_hi]);
  if (s < e) {
    // load a clamped batch of 4 records; zero weights of padded slots
    auto LD4 = [&](int j, Rec* rb) {
#pragma unroll
      for (int u = 0; u < 4; ++u) {
        int idx = (j + u < e) ? (j + u) : (e - 1);
        rb[u] = recs[idx];
        if (j + u >= e) { rb[u].b01 = 0u; rb[u].b23 = 0u; }
      }
    };
    Rec cur0, cur1, cur2, cur3;
    { Rec rb[4]; LD4(s, rb); cur0 = rb[0]; cur1 = rb[1]; cur2 = rb[2]; cur3 = rb[3]; }
    for (int j = s; j < e; j += 4) {
      // issue x-loads for current batch immediately (records already resolved)
      unsigned int xp0 = *(const unsigned int*)(Xb + (size_t)cur0.src * D + l2);
      unsigned int xp1 = *(const unsigned int*)(Xb + (size_t)cur1.src * D + l2);
      unsigned int xp2 = *(const unsigned int*)(Xb + (size_t)cur2.src * D + l2);
      unsigned int xp3 = *(const unsigned int*)(Xb + (size_t)cur3.src * D + l2);
      // prefetch next batch's records under the x-load latency
      bool more = (j + 4) < e;
      Rec nb[4];
      if (more) LD4(j + 4, nb);
      ACC(cur0, xp0); ACC(cur1, xp1); ACC(cur2, xp2); ACC(cur3, xp3);
      if (more) { cur0 = nb[0]; cur1 = nb[1]; cur2 = nb[2]; cur3 = nb[3]; }
    }
  }

  // vectorized bf16 writeback: 16B/lane chunks over the KCc*128 row
  unsigned short* gr = Gc + (size_t)dst * ((size_t)KCc * D);
  for (int t = l; t < KCc * 16; t += 64) {
    const float* src = A + (t >> 4) * D + (t & 15) * 8;
    float4 v0 = *(const float4*)(src);
    float4 v1 = *(const float4*)(src + 4);
    u32x4 pk;
    pk[0] = (unsigned int)f2bf(v0.x) | ((unsigned int)f2bf(v0.y) << 16);
    pk[1] = (unsigned int)f2bf(v0.z) | ((unsigned int)f2bf(v0.w) << 16);
    pk[2] = (unsigned int)f2bf(v1.x) | ((unsigned int)f2bf(v1.y) << 16);
    pk[3] = (unsigned int)f2bf(v1.z) | ((unsigned int)f2bf(v1.w) << 16);
    *(u32x4*)(gr + (size_t)t * 8) = pk;
  }
}

// ---------------- bf16 MFMA GEMM: Y[N,128] (+)= Gc[N,KCc*128] @ W[kchunk] ----
// 128x128 tile, 4 waves, BK=64, global_load_lds w/ pre-swizzled source (T2),
// 2-phase double-buffered pipeline.

__global__ __launch_bounds__(256) void gemm_kernel(
    const unsigned short* __restrict__ G, const unsigned short* __restrict__ WT,
    float* __restrict__ Y, int N, int KCc, int kc0, int first) {
  __shared__ __attribute__((aligned(16))) char At[2][16384];
  __shared__ __attribute__((aligned(16))) char Bt[2][16384];
  const int tid = threadIdx.x;
  const int w = tid >> 6;
  const int l = tid & 63;
  const int m0 = blockIdx.x * 128;
  const size_t ldG = (size_t)KCc * 256;  // bytes per G row
  const size_t ldW = (size_t)NK * 256;   // 6400 bytes per WT row

  const int lrow = l >> 3;                       // row within 8-row group
  const int scol = ((l & 7) * 16) ^ (lrow << 4); // swizzled source column byte

  f32x4 acc[2][8];
#pragma unroll
  for (int mr = 0; mr < 2; ++mr)
#pragma unroll
    for (int nc = 0; nc < 8; ++nc) {
      if (first) {
        acc[mr][nc] = (f32x4){0.f, 0.f, 0.f, 0.f};
      } else {
        int col = nc * 16 + (l & 15);
#pragma unroll
        for (int j = 0; j < 4; ++j) {
          int row = m0 + w * 32 + mr * 16 + (l >> 4) * 4 + j;
          acc[mr][nc][j] = (row < N) ? Y[(size_t)row * D + col] : 0.f;
        }
      }
    }

  const int steps = KCc * 2;
  auto STAGE = [&](int kt, int b) {
#pragma unroll
    for (int i = 0; i < 4; ++i) {  // A: 8 G-rows per load
      int row = w * 32 + i * 8 + lrow;
      int node = m0 + row;
      if (node > N - 1) node = N - 1;
      const char* src = (const char*)G + (size_t)node * ldG + kt * 128 + scol;
      __builtin_amdgcn_global_load_lds((gv_t*)src, (lv_t*)(At[b] + (w * 4 + i) * 1024),
                                       16, 0, 0);
    }
#pragma unroll
    for (int i = 0; i < 4; ++i) {  // B from WT (n-major)
      int nr = w * 32 + i * 8 + lrow;
      const char* src = (const char*)WT + (size_t)nr * ldW + kc0 * 256 + kt * 128 + scol;
      __builtin_amdgcn_global_load_lds((gv_t*)src, (lv_t*)(Bt[b] + (w * 4 + i) * 1024),
                                       16, 0, 0);
    }
  };

  STAGE(0, 0);
  __syncthreads();  // drains vmcnt(0): buf0 ready
  for (int kt = 0; kt < steps; ++kt) {
    const int cur = kt & 1;
    if (kt + 1 < steps) STAGE(kt + 1, cur ^ 1);  // issue next tile's loads now
#pragma unroll
    for (int ks = 0; ks < 2; ++ks) {
      int kb = ks * 64 + (l >> 4) * 16;
      bf16x8 a[2], b[8];
#pragma unroll
      for (int mr = 0; mr < 2; ++mr) {
        int r = w * 32 + mr * 16 + (l & 15);
        a[mr] = *(const bf16x8*)(At[cur] + r * 128 + (kb ^ ((r & 7) << 4)));
      }
#pragma unroll
      for (int nc = 0; nc < 8; ++nc) {
        int nr = nc * 16 + (l & 15);
        b[nc] = *(const bf16x8*)(Bt[cur] + nr * 128 + (kb ^ ((nr & 7) << 4)));
      }
#pragma unroll
      for (int mr = 0; mr < 2; ++mr)
#pragma unroll
        for (int nc = 0; nc < 8; ++nc)
          acc[mr][nc] =
              __builtin_amdgcn_mfma_f32_16x16x32_bf16(a[mr], b[nc], acc[mr][nc], 0, 0, 0);
    }
    __syncthreads();  // next buf ready, all reads of cur done
  }

#pragma unroll
  for (int mr = 0; mr < 2; ++mr)
#pragma unroll
    for (int nc = 0; nc < 8; ++nc) {
      int col = nc * 16 + (l & 15);
#pragma unroll
      for (int j = 0; j < 4; ++j) {
        int row = m0 + w * 32 + mr * 16 + (l >> 4) * 4 + j;
        if (row < N) Y[(size_t)row * D + col] = acc[mr][nc][j];
      }
    }
}

// ---------------- per-row l2norm / finalize ---------------------------------

__global__ __launch_bounds__(256) void l2norm_x_kernel(const float* __restrict__ x,
    float* __restrict__ out, unsigned short* __restrict__ xbf, int N) {
  int g = blockIdx.x * 256 + threadIdx.x;
  int n = g >> 6, lane = g & 63;
  if (n >= N) return;
  float2 v = *(const float2*)(x + (size_t)n * D + lane * 2);
  float ss = v.x * v.x + v.y * v.y;
#pragma unroll
  for (int m = 1; m < 64; m <<= 1) ss += __shfl_xor(ss, m, 64);
  float r = 1.0f / fmaxf(sqrtf(ss), 1e-12f);
  *(float2*)(out + (size_t)n * OD + lane * 2) = make_float2(v.x * r, v.y * r);
  unsigned int pk = (unsigned int)f2bf(v.x) | ((unsigned int)f2bf(v.y) << 16);
  *(unsigned int*)(xbf + (size_t)n * D + lane * 2) = pk;
}

__global__ __launch_bounds__(256) void finalize_kernel(const float* __restrict__ y,
    const int* __restrict__ deg, const float* __restrict__ bias, float* __restrict__ out,
    unsigned short* __restrict__ xnext, int N) {
  int g = blockIdx.x * 256 + threadIdx.x;
  int n = g >> 6, lane = g & 63;
  if (n >= N) return;
  float inv = 1.0f / (float)max(deg[n], 1);
  float2 a = *(const float2*)(y + (size_t)n * D + lane * 2);
  float2 b = *(const float2*)(bias + lane * 2);
  float h0 = a.x * inv + b.x;
  float h1 = a.y * inv + b.y;
  float ss = h0 * h0 + h1 * h1;
#pragma unroll
  for (int m = 1; m < 64; m <<= 1) ss += __shfl_xor(ss, m, 64);
  float r = 1.0f / fmaxf(sqrtf(ss), 1e-12f);
  *(float2*)(out + (size_t)n * OD + lane * 2) = make_float2(h0 * r, h1 * r);
  if (xnext) {
    unsigned int pk = (unsigned int)f2bf(fmaxf(h0, 0.f)) |
                      ((unsigned int)f2bf(fmaxf(h1, 0.f)) << 16);
    *(unsigned int*)(xnext + (size_t)n * D + lane * 2) = pk;
  }
}

// ---------------- launch -----------------------------------------------------

extern "C" void kernel_launch(void* const* d_in, const int* in_sizes, int n_in,
                              void* d_out, int out_size, void* d_ws, size_t ws_size,
                              hipStream_t stream) {
  const float* x    = (const float*)d_in[0];
  const int*   ei   = (const int*)d_in[1];
  const float* attr = (const float*)d_in[2];
  const float* w0   = (const float*)d_in[3];
  const float* b0   = (const float*)d_in[4];
  const float* w1   = (const float*)d_in[5];
  const float* b1   = (const float*)d_in[6];
  float* out = (float*)d_out;

  const int N = in_sizes[0] / D;
  const int E = in_sizes[1] / 2;
  const int* srcA = ei;
  const int* dstA = ei + E;
  const int M3 = N * 3;

  char* p = (char*)d_ws;
  auto carve = [&](size_t bytes) -> char* {
    char* r = p;
    p += (bytes + 255) & ~(size_t)255;
    return r;
  };
  unsigned short* xbf    = (unsigned short*)carve((size_t)N * D * 2);
  unsigned short* xtmp   = (unsigned short*)carve((size_t)N * D * 2);
  float*          ygemm  = (float*)carve((size_t)N * D * 4);
  int*            deg    = (int*)carve((size_t)N * 4);
  int*            cnt3   = (int*)carve((size_t)M3 * 4);
  int*            base3  = (int*)carve(((size_t)M3 + 1) * 4);
  int*            cursor = (int*)carve((size_t)M3 * 4);
  int*            bsum   = (int*)carve(4096);
  Rec*            recs   = (Rec*)carve((size_t)E * sizeof(Rec));
  unsigned short* WT0    = (unsigned short*)carve((size_t)128 * NK * D * 2);
  unsigned short* WT1    = (unsigned short*)carve((size_t)128 * NK * D * 2);
  size_t used = (size_t)(p - (char*)d_ws);
  size_t remain = (ws_size > used) ? (ws_size - used) : 0;
  int KCg = (int)(remain / ((size_t)N * D * 2));  // bf16 G bytes per k
  if (KCg > KCMAX) KCg = KCMAX;
  if (KCg < 1) KCg = 1;
  unsigned short* Gc = (unsigned short*)carve((size_t)N * (size_t)KCg * D * 2);
  (void)n_in; (void)out_size;

  hipMemsetAsync(deg, 0, (size_t)N * 4, stream);
  hipMemsetAsync(cnt3, 0, (size_t)M3 * 4, stream);

  int eb = (E + 255) / 256;
  count3_kernel<<<eb, 256, 0, stream>>>(dstA, attr, E, deg, cnt3);
  int nblk_a = (M3 + 1 + 1023) / 1024;
  scan_a_kernel<<<nblk_a, 1024, 0, stream>>>(cnt3, M3, base3, bsum);
  scan_b_kernel<<<1, 256, 0, stream>>>(bsum, nblk_a);
  scan_c_kernel<<<(M3 + 1 + 255) / 256, 256, 0, stream>>>(base3, cursor, bsum, M3);
  fill_kernel<<<eb, 256, 0, stream>>>(srcA, dstA, attr, E, cursor, recs);
  int wtb = (128 * NK * D + 255) / 256;
  wt_kernel<<<dim3(wtb, 2), 256, 0, stream>>>(w0, w1, WT0, WT1);

  int nb = (N * 64 + 255) / 256;
  l2norm_x_kernel<<<nb, 256, 0, stream>>>(x, out, xbf, N);

  int gbg = (N + 3) / 4;              // gather: 4 waves/block, wave per dst
  int gbm = (N + 127) / 128;          // gemm: 128-row tiles
  const unsigned short* xin = xbf;
  const float* Bv[2] = {b0, b1};
  const unsigned short* WTl[2] = {WT0, WT1};
  for (int layer = 0; layer < 2; ++layer) {
    if (KCg >= KB0) {
      // pass 0: chunk [0,13) — classes {c0-only, straddle}
      gather_kernel<<<gbg, 256, 0, stream>>>(base3, recs, xin, Gc, N, KB0, 0, 0, 2);
      gemm_kernel<<<gbm, 256, 0, stream>>>(Gc, WTl[layer], ygemm, N, KB0, 0, 1);
      // pass 1: chunk [13,25) — classes {straddle, c1-only}
      gather_kernel<<<gbg, 256, 0, stream>>>(base3, recs, xin, Gc, N, NK - KB0, KB0, 1, 3);
      gemm_kernel<<<gbm, 256, 0, stream>>>(Gc, WTl[layer], ygemm, N, NK - KB0, KB0, 0);
    } else {
      int first = 1;
      for (int kc0 = 0; kc0 < NK; kc0 += KCg) {
        int KCc = min(KCg, NK - kc0);
        gather_kernel<<<gbg, 256, 0, stream>>>(base3, recs, xin, Gc, N, KCc, kc0, 0, 3);
        gemm_kernel<<<gbm, 256, 0, stream>>>(Gc, WTl[layer], ygemm, N, KCc, kc0, first);
        first = 0;
      }
    }
    finalize_kernel<<<nb, 256, 0, stream>>>(ygemm, deg, Bv[layer], out + D * (layer + 1),
                                            layer == 0 ? xtmp : nullptr, N);
    xin = xtmp;
  }
}